// Round 10
// baseline (133.046 us; speedup 1.0000x reference)
//
#include <hip/hip_runtime.h>

typedef float v2f __attribute__((ext_vector_type(2)));

#define HW      1024   // H*W = BN channel count
#define NLAYERS 30
#define TPB     128    // TWO waves per channel, 32 elems/thread

// ---------------------------------------------------------------------------
// DPP wave64 sum (pure VALU); lane 63 ends with the wave total.
// ---------------------------------------------------------------------------
template <int CTRL, int RMASK>
__device__ __forceinline__ float dpp_add(float x) {
    int t = __builtin_amdgcn_update_dpp(0, __builtin_bit_cast(int, x),
                                        CTRL, RMASK, 0xf, true);
    return x + __builtin_bit_cast(float, t);
}
__device__ __forceinline__ float wave_sum_l63(float x) {
    x = dpp_add<0x111, 0xf>(x);   // row_shr:1
    x = dpp_add<0x112, 0xf>(x);   // row_shr:2
    x = dpp_add<0x114, 0xf>(x);   // row_shr:4
    x = dpp_add<0x118, 0xf>(x);   // row_shr:8
    x = dpp_add<0x142, 0xa>(x);   // row_bcast15 -> rows 1,3
    x = dpp_add<0x143, 0xc>(x);   // row_bcast31 -> rows 2,3
    return x;                     // lane 63 = total
}

// ---------------------------------------------------------------------------
// Fused 30-layer ODE, ONE channel per 128-thread block (2 waves, 32 elems/
// thread). Minimal sync scope: the per-layer rendezvous is a TWO-wave
// __syncthreads (vs R5's 4-wave) and each wave carries 2x the instructions
// between syncs — per-SIMD issue per layer drops ~40% vs R5, and there is
// exactly ONE barrier partner. Parity double-buffered red[] keeps the
// single-barrier-per-layer protocol race-free (waves stay <=1 layer apart).
//
// m[l,c] and dt are prefetched one layer ahead from GLOBAL (30 KB, L3/L2-
// resident; VMEM pipe overlaps the DPP/VALU chain) — no 30 KB LDS staging.
// Element map: thread u owns e = u + 128j (j=0..31); packed as v2f pair
// k2: .x  e = u+256*k2 (c=u), .y  e = u+128+256*k2 (c=u+128) -> m2={m[u],m[u+128]}.
// Epilogue algebra (no z storage): y' = (1-dt)*y + med3(gd*m*x1 + gd*y + bd,
// 0, 6dt), gd = g*dt, bd = bb*dt.
// XCD swizzle: contiguous 128-wide p-range per XCD -> every 64B x/out line
// touched by ONE XCD L2 (R4: 220 -> 25 MB hbm traffic).
// ---------------------------------------------------------------------------
__global__ __launch_bounds__(TPB) void ode_fused(const float* __restrict__ x,
                                                 const float* __restrict__ delta_t,
                                                 const float* __restrict__ matrices,
                                                 const float* __restrict__ gamma,
                                                 const float* __restrict__ beta,
                                                 float* __restrict__ out) {
    const int bid  = blockIdx.x;                  // 0..1023
    const int p    = ((bid & 7) << 7) | (bid >> 3);
    const int u    = threadIdx.x;                 // 0..127
    const int w    = u >> 6;                      // wave 0/1
    const int lane = u & 63;

    __shared__ __align__(16) float2 red[2][2];    // [parity][wave] = (s, q)

    // Gather channel p: 32 scalar loads, stride 4 KB (owning-XCD L2 serves).
    v2f x1[16], y[16];
#pragma unroll
    for (int k2 = 0; k2 < 16; ++k2) {
        const int e0 = u + 256 * k2;
        x1[k2].x = x[(size_t)e0 * HW + p];
        x1[k2].y = x[(size_t)(e0 + 128) * HW + p];
        y[k2] = x1[k2];
    }

    const float gp = gamma[p];
    const float bp = beta[p];

    // Layer-0 params (L3-resident global loads).
    float m0  = matrices[u];
    float m1  = matrices[u + 128];
    float dtl = __builtin_amdgcn_fmed3f(delta_t[0], 0.0f, 6.0f);

    for (int l = 0; l < NLAYERS; ++l) {
        const v2f m2 = {m0, m1};

        // z = fma(m, x1, y); accumulate (sum, sumsq); z not stored.
        v2f sA = {0.f, 0.f}, sB = {0.f, 0.f};
        v2f qA = {0.f, 0.f}, qB = {0.f, 0.f};
#pragma unroll
        for (int k = 0; k < 16; k += 2) {
            const v2f za = __builtin_elementwise_fma(m2, x1[k], y[k]);
            const v2f zb = __builtin_elementwise_fma(m2, x1[k + 1], y[k + 1]);
            sA += za; sB += zb;
            qA = __builtin_elementwise_fma(za, za, qA);
            qB = __builtin_elementwise_fma(zb, zb, qB);
        }
        const v2f sv = sA + sB;
        const v2f qv = qA + qB;
        const float s = wave_sum_l63(sv.x + sv.y);
        const float q = wave_sum_l63(qv.x + qv.y);

        const int par = l & 1;
        if (lane == 63) { float2 t2; t2.x = s; t2.y = q; red[par][w] = t2; }

        // Prefetch next layer's params (VMEM pipe; overlaps barrier wait).
        const int ln = (l + 1 < NLAYERS) ? l + 1 : l;
        const float m0n = matrices[ln * 256 + u];
        const float m1n = matrices[ln * 256 + u + 128];
        const float dtn = __builtin_amdgcn_fmed3f(delta_t[ln], 0.0f, 6.0f);

        __syncthreads();   // 2-wave rendezvous (cheapest possible)

        const float4 r = *(const float4*)&red[par][0];   // s0,q0,s1,q1
        const float S = r.x + r.z;
        const float Q = r.y + r.w;

        const float mean = S * (1.0f / 4096.0f);
        const float var  = fmaf(-mean, mean, Q * (1.0f / 4096.0f));
        const float rstd = rsqrtf(var + 1e-5f);
        const float g    = gp * rstd;
        const float bb   = fmaf(-mean, g, bp);
        const float gd = g * dtl, bd = bb * dtl, sixdt = 6.0f * dtl;
        const float om = 1.0f - dtl;
        const v2f gd2 = {gd, gd}, bd2 = {bd, bd}, om2 = {om, om};
        const v2f gm2 = {gd * m0, gd * m1};
#pragma unroll
        for (int k = 0; k < 16; ++k) {
            v2f a = __builtin_elementwise_fma(y[k], gd2, bd2);   // gd*y + bd
            a = __builtin_elementwise_fma(x1[k], gm2, a);        // + gd*m*x1
            a.x = __builtin_amdgcn_fmed3f(a.x, 0.0f, sixdt);     // dt*relu6(.)
            a.y = __builtin_amdgcn_fmed3f(a.y, 0.0f, sixdt);
            y[k] = __builtin_elementwise_fma(om2, y[k], a);      // (1-dt)y + a
        }
        m0 = m0n; m1 = m1n; dtl = dtn;
    }

    // Scatter out = y + x1; partial lines merge in the owning XCD's L2.
#pragma unroll
    for (int k2 = 0; k2 < 16; ++k2) {
        const int e0 = u + 256 * k2;
        out[(size_t)e0 * HW + p]         = y[k2].x + x1[k2].x;
        out[(size_t)(e0 + 128) * HW + p] = y[k2].y + x1[k2].y;
    }
}

extern "C" void kernel_launch(void* const* d_in, const int* in_sizes, int n_in,
                              void* d_out, int out_size, void* d_ws, size_t ws_size,
                              hipStream_t stream) {
    const float* x        = (const float*)d_in[0];   // [16,256,32,32]
    const float* delta_t  = (const float*)d_in[1];   // [30,1]
    const float* matrices = (const float*)d_in[2];   // [30,1,1,16,16]
    const float* gamma    = (const float*)d_in[3];   // [1024]
    const float* beta     = (const float*)d_in[4];   // [1024]
    float* out = (float*)d_out;

    ode_fused<<<dim3(HW), dim3(TPB), 0, stream>>>(x, delta_t, matrices,
                                                  gamma, beta, out);
}